// Round 1
// baseline (413.995 us; speedup 1.0000x reference)
//
#include <hip/hip_runtime.h>
#include <math.h>

// Quantizer: per-group(128) abs-max -> PoT scale (ceil(log2), clamp [0, 2^W-1])
// -> round-half-even, clamp [-128,127] -> dequantize (fused path).
// Input: 8192x8192 fp32 (64M elems). Output: same shape fp32.
//
// One float4 per thread => 32 lanes per 128-elem group. Butterfly shfl_xor
// with masks <=16 reduces each aligned 32-lane subgroup independently
// (wave=64 covers exactly 2 groups).

__global__ __launch_bounds__(256) void quant_dequant_kernel(
    const float* __restrict__ t,
    const int* __restrict__ w_scale_bits_p,
    float* __restrict__ out,
    int n4)  // number of float4 elements
{
    int tid = blockIdx.x * blockDim.x + threadIdx.x;
    if (tid >= n4) return;

    const float4* __restrict__ tin = (const float4*)t;
    float4* __restrict__ tout = (float4*)out;

    float4 v = tin[tid];

    // local abs-max of 4 elements
    float a = fmaxf(fmaxf(fabsf(v.x), fabsf(v.y)),
                    fmaxf(fabsf(v.z), fabsf(v.w)));

    // reduce across the 32 lanes that share this 128-elem group.
    // xor masks 16,8,4,2,1 keep lanes within their aligned 32-lane subgroup.
    a = fmaxf(a, __shfl_xor(a, 16));
    a = fmaxf(a, __shfl_xor(a, 8));
    a = fmaxf(a, __shfl_xor(a, 4));
    a = fmaxf(a, __shfl_xor(a, 2));
    a = fmaxf(a, __shfl_xor(a, 1));

    int s_max = (1 << w_scale_bits_p[0]) - 1;  // 2^W_SCALE_BITS - 1

    float scale;
    if (a > 0.0f) {
        float sc = a / 127.0f;          // fp32 division, matches np
        // exact ceil(log2(sc)): sc = mant * 2^e, mant in [0.5, 1)
        // log2(sc) = e + log2(mant); log2(mant) in [-1, 0)
        // ceil = (mant == 0.5) ? e - 1 : e
        int e;
        float mant = frexpf(sc, &e);
        int s = (mant == 0.5f) ? (e - 1) : e;
        s = min(max(s, 0), s_max);
        scale = (float)(1 << s);        // 2^s, exact in fp16/fp32
    } else {
        // t_max==0: ref gives s clamped to 0 -> scale=1, q=0
        scale = 1.0f;
    }

    float inv = 1.0f / scale;           // exact (power of two)

    float4 o;
    o.x = fminf(fmaxf(rintf(v.x * inv), -128.0f), 127.0f) * scale;
    o.y = fminf(fmaxf(rintf(v.y * inv), -128.0f), 127.0f) * scale;
    o.z = fminf(fmaxf(rintf(v.z * inv), -128.0f), 127.0f) * scale;
    o.w = fminf(fmaxf(rintf(v.w * inv), -128.0f), 127.0f) * scale;

    tout[tid] = o;
}

extern "C" void kernel_launch(void* const* d_in, const int* in_sizes, int n_in,
                              void* d_out, int out_size, void* d_ws, size_t ws_size,
                              hipStream_t stream) {
    const float* t = (const float*)d_in[0];
    // d_in[1] = fused (unused; fused path implemented)
    const int* w_scale_bits = (const int*)d_in[2];
    float* out = (float*)d_out;

    int n = in_sizes[0];          // 64M
    int n4 = n / 4;               // 16M float4s (n is a multiple of 128)

    const int block = 256;
    int grid = (n4 + block - 1) / block;

    quant_dequant_kernel<<<grid, block, 0, stream>>>(t, w_scale_bits, out, n4);
}

// Round 3
// 413.113 us; speedup vs baseline: 1.0021x; 1.0021x over previous
//
#include <hip/hip_runtime.h>
#include <math.h>

// Quantizer: per-group(128) abs-max -> PoT scale (ceil(log2), clamp [0, 2^W-1])
// -> round-half-even, clamp [-128,127] -> dequantize (fused path).
// Input: 8192x8192 fp32 (64M elems). Output: same shape fp32.
//
// One v4f per thread => 32 lanes per 128-elem group. Butterfly shfl_xor
// with masks <=16 reduces each aligned 32-lane subgroup independently
// (wave=64 covers exactly 2 groups). Touch-once streams -> nontemporal
// load/store (native clang vector type; HIP float4 struct is rejected).

typedef float v4f __attribute__((ext_vector_type(4)));

__global__ __launch_bounds__(256) void quant_dequant_kernel(
    const float* __restrict__ t,
    const int* __restrict__ w_scale_bits_p,
    float* __restrict__ out,
    int n4)  // number of 4-float vectors
{
    int tid = blockIdx.x * blockDim.x + threadIdx.x;
    if (tid >= n4) return;

    const v4f* __restrict__ tin = (const v4f*)t;
    v4f* __restrict__ tout = (v4f*)out;

    v4f v = __builtin_nontemporal_load(&tin[tid]);

    // local abs-max of 4 elements
    float a = fmaxf(fmaxf(fabsf(v.x), fabsf(v.y)),
                    fmaxf(fabsf(v.z), fabsf(v.w)));

    // reduce across the 32 lanes that share this 128-elem group.
    // xor masks 16,8,4,2,1 keep lanes within their aligned 32-lane subgroup.
    a = fmaxf(a, __shfl_xor(a, 16));
    a = fmaxf(a, __shfl_xor(a, 8));
    a = fmaxf(a, __shfl_xor(a, 4));
    a = fmaxf(a, __shfl_xor(a, 2));
    a = fmaxf(a, __shfl_xor(a, 1));

    int s_max = (1 << w_scale_bits_p[0]) - 1;  // 2^W_SCALE_BITS - 1

    float scale;
    if (a > 0.0f) {
        float sc = a / 127.0f;          // fp32 division, matches np exactly
        // exact ceil(log2(sc)): sc = mant * 2^e, mant in [0.5, 1)
        // ceil(log2) = (mant == 0.5) ? e - 1 : e
        int e;
        float mant = frexpf(sc, &e);
        int s = (mant == 0.5f) ? (e - 1) : e;
        s = min(max(s, 0), s_max);
        scale = (float)(1 << s);        // 2^s, exact
    } else {
        scale = 1.0f;                   // t_max==0 -> s clamps to 0
    }

    float inv = 1.0f / scale;           // exact (power of two)

    v4f o;
    o.x = fminf(fmaxf(rintf(v.x * inv), -128.0f), 127.0f) * scale;
    o.y = fminf(fmaxf(rintf(v.y * inv), -128.0f), 127.0f) * scale;
    o.z = fminf(fmaxf(rintf(v.z * inv), -128.0f), 127.0f) * scale;
    o.w = fminf(fmaxf(rintf(v.w * inv), -128.0f), 127.0f) * scale;

    __builtin_nontemporal_store(o, &tout[tid]);
}

extern "C" void kernel_launch(void* const* d_in, const int* in_sizes, int n_in,
                              void* d_out, int out_size, void* d_ws, size_t ws_size,
                              hipStream_t stream) {
    const float* t = (const float*)d_in[0];
    // d_in[1] = fused (unused; fused path implemented)
    const int* w_scale_bits = (const int*)d_in[2];
    float* out = (float*)d_out;

    int n = in_sizes[0];          // 64M
    int n4 = n / 4;               // 16M 4-float vectors (n is a multiple of 128)

    const int block = 256;
    int grid = (n4 + block - 1) / block;

    quant_dequant_kernel<<<grid, block, 0, stream>>>(t, w_scale_bits, out, n4);
}